// Round 2
// baseline (79.175 us; speedup 1.0000x reference)
//
#include <hip/hip_runtime.h>
#include <hip/hip_cooperative_groups.h>
#include <math.h>

namespace cg = cooperative_groups;

#define BB 4
#define PP 16384
#define GG 512
#define HH 512
#define WW 512
#define CAP 160
#define NBLK 256
#define NTHR 256

// Workspace layout (bytes):
//   counts : [B][G] int      at 0                  (8 KB)
//   labels : [B][P] int      at 8192               (256 KB)
//   buckets: [B][G][CAP] int at 8192 + B*P*4       (1.31 MB)
#define WS_COUNTS(ws)  ((int*)(ws))
#define WS_LABELS(ws)  ((int*)((char*)(ws) + BB*GG*4))
#define WS_BUCKETS(ws) ((int*)((char*)(ws) + BB*GG*4 + BB*PP*4))

__device__ __forceinline__ float distf(float px, float py, float gx, float gy) {
#pragma clang fp contract(off)
    float dx = px - gx;
    float dy = py - gy;
    float a = dx * dx;
    float c = dy * dy;
    return sqrtf(a + c);   // matches XLA: separate mul/add/sqrt, no FMA contraction
}

// Single cooperative kernel: phase0 init -> sync -> phase1 label/scatter ->
// sync -> phase2 per-(b,g) nearest-candidate match.
__global__ void __launch_bounds__(NTHR) k_fused(const float* __restrict__ pred,
                                                const float* __restrict__ gt,
                                                const int* __restrict__ lm,
                                                int* __restrict__ counts,
                                                int* __restrict__ labels,
                                                int* __restrict__ buckets,
                                                float* __restrict__ out) {
    cg::grid_group grid = cg::this_grid();
    const int t = blockIdx.x * blockDim.x + threadIdx.x;   // [0, B*P) exactly

    // ---- phase 0: zero bucket counts (ws not re-poisoned between replays),
    //               write tgt = arange(G) per batch
    if (t < BB * GG) {
        counts[t] = 0;
        out[BB * GG + t] = (float)(t % GG);
    }
    grid.sync();

    // ---- phase 1: rounded+clipped pixel label per point; scatter into bucket
    {
        const int b = t / PP;
        float px = pred[2 * t + 0];
        float py = pred[2 * t + 1];
        int x = min(max((int)rintf(px), 0), WW - 1);   // round half-to-even, like jnp.round
        int y = min(max((int)rintf(py), 0), HH - 1);
        int lab = lm[(b * HH + y) * WW + x];
        labels[t] = lab;
        if (lab > 0) {
            int g = lab - 1;
            int slot = atomicAdd(&counts[b * GG + g], 1);
            if (slot < CAP) buckets[(b * GG + g) * CAP + slot] = t - b * PP;
        }
    }
    grid.sync();

    // ---- phase 2: one wave per (b,g), strided (1024 waves, 2048 pairs)
    const int lane = threadIdx.x & 63;
    const int wv0  = t >> 6;                       // 0..1023
    const int nwv  = (NBLK * NTHR) >> 6;           // 1024
    for (int wv = wv0; wv < BB * GG; wv += nwv) {
        const int b = wv / GG, g = wv % GG;
        float gx = gt[2 * (b * GG + g) + 0];
        float gy = gt[2 * (b * GG + g) + 1];
        int cnt = counts[b * GG + g];

        float bd = INFINITY;
        int   bi = 0x7fffffff;

        if (cnt == 0) {
            // no point inside mask g: argmin over ALL points (P(empty)~e^-32)
            for (int p = lane; p < PP; p += 64) {
                float px = pred[2 * (b * PP + p) + 0];
                float py = pred[2 * (b * PP + p) + 1];
                float d = distf(px, py, gx, gy);
                if (d < bd || (d == bd && p < bi)) { bd = d; bi = p; }
            }
        } else if (cnt <= CAP) {
            for (int e = lane; e < cnt; e += 64) {
                int p = buckets[(b * GG + g) * CAP + e];
                float px = pred[2 * (b * PP + p) + 0];
                float py = pred[2 * (b * PP + p) + 1];
                float d = distf(px, py, gx, gy);
                if (d < bd || (d == bd && p < bi)) { bd = d; bi = p; }
            }
        } else {
            // bucket overflow (CAP=160 vs mean 32: ~never): exact re-filter
            for (int p = lane; p < PP; p += 64) {
                if (labels[b * PP + p] == g + 1) {
                    float px = pred[2 * (b * PP + p) + 0];
                    float py = pred[2 * (b * PP + p) + 1];
                    float d = distf(px, py, gx, gy);
                    if (d < bd || (d == bd && p < bi)) { bd = d; bi = p; }
                }
            }
        }

        // wave butterfly reduce: (min d, then min original index) — order-invariant
        for (int off = 32; off > 0; off >>= 1) {
            float od = __shfl_xor(bd, off, 64);
            int   oi = __shfl_xor(bi, off, 64);
            if (od < bd || (od == bd && oi < bi)) { bd = od; bi = oi; }
        }

        if (lane == 0) {
            out[b * GG + g]               = (float)bi;  // src_idx
            out[2 * BB * GG + b * GG + g] = bd;         // costs (tgt from phase 0)
        }
    }
}

extern "C" void kernel_launch(void* const* d_in, const int* in_sizes, int n_in,
                              void* d_out, int out_size, void* d_ws, size_t ws_size,
                              hipStream_t stream) {
    const float* pred = (const float*)d_in[0];
    const float* gt   = (const float*)d_in[1];
    const int*   lm   = (const int*)d_in[2];
    float* out = (float*)d_out;

    int* counts  = WS_COUNTS(d_ws);
    int* labels  = WS_LABELS(d_ws);
    int* buckets = WS_BUCKETS(d_ws);

    void* args[] = { (void*)&pred, (void*)&gt, (void*)&lm,
                     (void*)&counts, (void*)&labels, (void*)&buckets, (void*)&out };
    hipLaunchCooperativeKernel((const void*)k_fused, dim3(NBLK), dim3(NTHR),
                               args, 0, stream);
}

// Round 3
// 28.750 us; speedup vs baseline: 2.7539x; 2.7539x over previous
//
#include <hip/hip_runtime.h>
#include <math.h>

#define BB 4
#define PP 16384
#define GG 512
#define HH 512
#define WW 512
#define NTHR 512
#define GPB 8          // g's per block (one per wave)
#define BPB 64         // blocks per batch = GG/GPB
#define CAPL 96        // LDS bucket capacity per g (mean occupancy 32; P(>96) ~ 1e-19)

__device__ __forceinline__ float distf(float px, float py, float gx, float gy) {
#pragma clang fp contract(off)
    float dx = px - gx;
    float dy = py - gy;
    float a = dx * dx;
    float c = dy * dy;
    return sqrtf(a + c);   // matches XLA: separate mul/add/sqrt, no FMA contraction
}

// One block per (batch, 8-g range). Block-local LDS buckets -> zero global
// scratch, zero cross-block dependencies, one dispatch.
__global__ void __launch_bounds__(NTHR) k_match(const float* __restrict__ pred,
                                                const float* __restrict__ gt,
                                                const int* __restrict__ lm,
                                                float* __restrict__ out) {
    __shared__ int   cnt[GPB];
    __shared__ float bxy[GPB][CAPL][2];
    __shared__ int   bidx[GPB][CAPL];

    const int b     = blockIdx.x / BPB;
    const int gbase = (blockIdx.x % BPB) * GPB;
    const int tid   = threadIdx.x;

    if (tid < GPB) cnt[tid] = 0;
    __syncthreads();

    const float* predb = pred + (size_t)b * PP * 2;
    const int*   lmb   = lm + (size_t)b * HH * WW;

    // ---- Phase A: bucket points whose pixel label falls in [gbase+1, gbase+GPB]
    #pragma unroll 4
    for (int p = tid; p < PP; p += NTHR) {
        float px = predb[2 * p + 0];
        float py = predb[2 * p + 1];
        int x = min(max((int)rintf(px), 0), WW - 1);   // round half-to-even = jnp.round
        int y = min(max((int)rintf(py), 0), HH - 1);
        int lg = lmb[y * WW + x] - 1 - gbase;          // local g index
        if ((unsigned)lg < GPB) {
            int slot = atomicAdd(&cnt[lg], 1);         // LDS atomic, block-local
            if (slot < CAPL) {
                bxy[lg][slot][0] = px;
                bxy[lg][slot][1] = py;
                bidx[lg][slot]   = p;
            }
        }
    }
    __syncthreads();

    // ---- Phase B: wave w resolves g = gbase + w
    const int w    = tid >> 6;
    const int lane = tid & 63;
    const int g    = gbase + w;
    const float gx = gt[(size_t)(b * GG + g) * 2 + 0];
    const float gy = gt[(size_t)(b * GG + g) * 2 + 1];
    const int n = cnt[w];

    float bd = INFINITY;
    int   bi = 0x7fffffff;

    if (n == 0) {
        // empty mask: argmin over ALL points (reference fallback); ~never taken
        for (int p = lane; p < PP; p += 64) {
            float d = distf(predb[2 * p], predb[2 * p + 1], gx, gy);
            if (d < bd || (d == bd && p < bi)) { bd = d; bi = p; }
        }
    } else if (n <= CAPL) {
        for (int e = lane; e < n; e += 64) {
            float d = distf(bxy[w][e][0], bxy[w][e][1], gx, gy);
            int p = bidx[w][e];
            if (d < bd || (d == bd && p < bi)) { bd = d; bi = p; }
        }
    } else {
        // bucket overflow (~impossible): exact re-filter from global
        for (int p = lane; p < PP; p += 64) {
            float px = predb[2 * p], py = predb[2 * p + 1];
            int x = min(max((int)rintf(px), 0), WW - 1);
            int y = min(max((int)rintf(py), 0), HH - 1);
            if (lmb[y * WW + x] == g + 1) {
                float d = distf(px, py, gx, gy);
                if (d < bd || (d == bd && p < bi)) { bd = d; bi = p; }
            }
        }
    }

    // wave butterfly reduce: (min d, then min original index) — order-invariant
    for (int off = 32; off > 0; off >>= 1) {
        float od = __shfl_xor(bd, off, 64);
        int   oi = __shfl_xor(bi, off, 64);
        if (od < bd || (od == bd && oi < bi)) { bd = od; bi = oi; }
    }

    if (lane == 0) {
        int o = b * GG + g;
        out[o]               = (float)bi;   // src_idx
        out[BB * GG + o]     = (float)g;    // tgt_idx
        out[2 * BB * GG + o] = bd;          // costs
    }
}

extern "C" void kernel_launch(void* const* d_in, const int* in_sizes, int n_in,
                              void* d_out, int out_size, void* d_ws, size_t ws_size,
                              hipStream_t stream) {
    const float* pred = (const float*)d_in[0];
    const float* gt   = (const float*)d_in[1];
    const int*   lm   = (const int*)d_in[2];
    float* out = (float*)d_out;

    k_match<<<dim3(BB * BPB), dim3(NTHR), 0, stream>>>(pred, gt, lm, out);
}

// Round 4
// 15.743 us; speedup vs baseline: 5.0292x; 1.8262x over previous
//
#include <hip/hip_runtime.h>
#include <math.h>

#define BB 4
#define PP 16384
#define GG 512
#define HH 512
#define WW 512
#define GPB 8            // g's per block in kernel 2 (one wave per g)
#define BPB 64           // blocks per batch = GG/GPB
#define NTHR2 512
#define CAPL 128         // LDS bucket capacity (mean 32; P(>128) astronomically small)

__device__ __forceinline__ float distf(float px, float py, float gx, float gy) {
#pragma clang fp contract(off)
    float dx = px - gx;
    float dy = py - gy;
    float a = dx * dx;
    float c = dy * dy;
    return sqrtf(a + c);   // matches XLA: separate mul/add/sqrt, no FMA contraction
}

// Kernel 1: each point labeled exactly once (the only random-gather pass).
// Pure writes to labels[] -> no init, no atomics, no workspace counts.
__global__ void k_label(const float* __restrict__ pred, const int* __restrict__ lm,
                        int* __restrict__ labels) {
    int t = blockIdx.x * blockDim.x + threadIdx.x;   // [0, B*P) exactly
    int b = t >> 14;                                  // t / PP
    float px = pred[2 * t + 0];
    float py = pred[2 * t + 1];
    int x = min(max((int)rintf(px), 0), WW - 1);      // round half-to-even = jnp.round
    int y = min(max((int)rintf(py), 0), HH - 1);
    labels[t] = lm[((b << 9) + y) * WW + x];          // b*HH*WW + y*WW + x
}

// Kernel 2: one block per (batch, 8-g range). Coalesced int4 scan of the
// block's labels slice -> LDS index buckets -> one wave per g resolves.
__global__ void __launch_bounds__(NTHR2) k_match(const float* __restrict__ pred,
                                                 const float* __restrict__ gt,
                                                 const int* __restrict__ labels,
                                                 float* __restrict__ out) {
    __shared__ int cnt[GPB];
    __shared__ int bidx[GPB][CAPL];

    const int b     = blockIdx.x / BPB;
    const int gbase = (blockIdx.x % BPB) * GPB;
    const int tid   = threadIdx.x;

    if (tid < GPB) cnt[tid] = 0;
    __syncthreads();

    const float* predb = pred + (size_t)b * PP * 2;
    const int*   labb  = labels + (size_t)b * PP;

    // ---- Phase A: coalesced label scan, bucket indices for our 8 g's
    const int4* lab4 = (const int4*)labb;
    #pragma unroll
    for (int i = tid; i < PP / 4; i += NTHR2) {       // 8 iterations
        int4 lv = lab4[i];
        int p0 = i * 4;
        int lg;
        lg = lv.x - 1 - gbase; if ((unsigned)lg < GPB) { int s = atomicAdd(&cnt[lg], 1); if (s < CAPL) bidx[lg][s] = p0 + 0; }
        lg = lv.y - 1 - gbase; if ((unsigned)lg < GPB) { int s = atomicAdd(&cnt[lg], 1); if (s < CAPL) bidx[lg][s] = p0 + 1; }
        lg = lv.z - 1 - gbase; if ((unsigned)lg < GPB) { int s = atomicAdd(&cnt[lg], 1); if (s < CAPL) bidx[lg][s] = p0 + 2; }
        lg = lv.w - 1 - gbase; if ((unsigned)lg < GPB) { int s = atomicAdd(&cnt[lg], 1); if (s < CAPL) bidx[lg][s] = p0 + 3; }
    }
    __syncthreads();

    // ---- Phase B: wave w resolves g = gbase + w
    const int w    = tid >> 6;
    const int lane = tid & 63;
    const int g    = gbase + w;
    const float gx = gt[(size_t)(b * GG + g) * 2 + 0];
    const float gy = gt[(size_t)(b * GG + g) * 2 + 1];
    const int n = cnt[w];

    float bd = INFINITY;
    int   bi = 0x7fffffff;

    if (n == 0) {
        // empty mask: argmin over ALL points (reference fallback); ~never taken
        for (int p = lane; p < PP; p += 64) {
            float d = distf(predb[2 * p], predb[2 * p + 1], gx, gy);
            if (d < bd || (d == bd && p < bi)) { bd = d; bi = p; }
        }
    } else if (n <= CAPL) {
        for (int e = lane; e < n; e += 64) {          // 1 iteration typically
            int p = bidx[w][e];
            float d = distf(predb[2 * p], predb[2 * p + 1], gx, gy);
            if (d < bd || (d == bd && p < bi)) { bd = d; bi = p; }
        }
    } else {
        // bucket overflow (~impossible): exact coalesced re-filter
        for (int p = lane; p < PP; p += 64) {
            if (labb[p] == g + 1) {
                float d = distf(predb[2 * p], predb[2 * p + 1], gx, gy);
                if (d < bd || (d == bd && p < bi)) { bd = d; bi = p; }
            }
        }
    }

    // wave butterfly reduce: (min d, then min original index) — order-invariant
    for (int off = 32; off > 0; off >>= 1) {
        float od = __shfl_xor(bd, off, 64);
        int   oi = __shfl_xor(bi, off, 64);
        if (od < bd || (od == bd && oi < bi)) { bd = od; bi = oi; }
    }

    if (lane == 0) {
        int o = b * GG + g;
        out[o]               = (float)bi;   // src_idx
        out[BB * GG + o]     = (float)g;    // tgt_idx
        out[2 * BB * GG + o] = bd;          // costs
    }
}

extern "C" void kernel_launch(void* const* d_in, const int* in_sizes, int n_in,
                              void* d_out, int out_size, void* d_ws, size_t ws_size,
                              hipStream_t stream) {
    const float* pred = (const float*)d_in[0];
    const float* gt   = (const float*)d_in[1];
    const int*   lm   = (const int*)d_in[2];
    float* out = (float*)d_out;
    int* labels = (int*)d_ws;   // [B][P] int, written before read, no init needed

    k_label<<<dim3(BB * PP / 256), dim3(256), 0, stream>>>(pred, lm, labels);
    k_match<<<dim3(BB * BPB), dim3(NTHR2), 0, stream>>>(pred, gt, labels, out);
}

// Round 5
// 14.463 us; speedup vs baseline: 5.4743x; 1.0885x over previous
//
#include <hip/hip_runtime.h>
#include <math.h>

#define BB 4
#define PP 16384
#define GG 512
#define HH 512
#define WW 512
#define GPB 16           // g's per block in kernel 2 (one wave per g)
#define BPB 32           // blocks per batch = GG/GPB
#define NTHR2 1024       // 16 waves
#define CAPL 128         // LDS bucket capacity (mean 32; P(>128) ~ 1e-40)

typedef unsigned short u16;
typedef __attribute__((ext_vector_type(8))) unsigned short u16x8;

__device__ __forceinline__ float distf(float px, float py, float gx, float gy) {
#pragma clang fp contract(off)
    float dx = px - gx;
    float dy = py - gy;
    float a = dx * dx;
    float c = dy * dy;
    return sqrtf(a + c);   // matches XLA: separate mul/add/sqrt, no FMA contraction
}

// Kernel 1: each point labeled exactly once (the only random-gather pass).
// Pure u16 writes to labels[] -> no init, no atomics, no workspace counts.
__global__ void k_label(const float* __restrict__ pred, const int* __restrict__ lm,
                        u16* __restrict__ labels) {
    int t = blockIdx.x * blockDim.x + threadIdx.x;   // [0, B*P) exactly
    int b = t >> 14;                                  // t / PP
    float px = pred[2 * t + 0];
    float py = pred[2 * t + 1];
    int x = min(max((int)rintf(px), 0), WW - 1);      // round half-to-even = jnp.round
    int y = min(max((int)rintf(py), 0), HH - 1);
    labels[t] = (u16)lm[((b << 9) + y) * WW + x];     // b*HH*WW + y*WW + x
}

// Kernel 2: one block per (batch, 16-g range). Coalesced 16B scan of the
// block's u16 labels slice -> LDS index buckets -> one wave per g resolves.
__global__ void __launch_bounds__(NTHR2) k_match(const float* __restrict__ pred,
                                                 const float* __restrict__ gt,
                                                 const u16* __restrict__ labels,
                                                 float* __restrict__ out) {
    __shared__ int cnt[GPB];
    __shared__ int bidx[GPB][CAPL];

    const int b     = blockIdx.x / BPB;
    const int gbase = (blockIdx.x % BPB) * GPB;
    const int tid   = threadIdx.x;

    if (tid < GPB) cnt[tid] = 0;
    __syncthreads();

    const float2* predb = (const float2*)(pred + (size_t)b * PP * 2);
    const u16*    labb  = labels + (size_t)b * PP;

    // ---- Phase A: coalesced u16x8 label scan, bucket indices for our 16 g's
    const u16x8* lab8 = (const u16x8*)labb;
    #pragma unroll
    for (int i = tid; i < PP / 8; i += NTHR2) {       // 2 iterations
        u16x8 lv = lab8[i];
        int p0 = i * 8;
        #pragma unroll
        for (int j = 0; j < 8; ++j) {
            int lg = (int)lv[j] - 1 - gbase;
            if ((unsigned)lg < GPB) {
                int s = atomicAdd(&cnt[lg], 1);       // LDS atomic, block-local
                if (s < CAPL) bidx[lg][s] = p0 + j;
            }
        }
    }
    __syncthreads();

    // ---- Phase B: wave w resolves g = gbase + w
    const int w    = tid >> 6;
    const int lane = tid & 63;
    const int g    = gbase + w;
    const float gx = gt[(size_t)(b * GG + g) * 2 + 0];
    const float gy = gt[(size_t)(b * GG + g) * 2 + 1];
    const int n = cnt[w];

    float bd = INFINITY;
    int   bi = 0x7fffffff;

    if (n == 0) {
        // empty mask: argmin over ALL points (reference fallback); ~never taken
        for (int p = lane; p < PP; p += 64) {
            float2 c = predb[p];
            float d = distf(c.x, c.y, gx, gy);
            if (d < bd || (d == bd && p < bi)) { bd = d; bi = p; }
        }
    } else if (n <= CAPL) {
        for (int e = lane; e < n; e += 64) {          // 1 iteration typically
            int p = bidx[w][e];
            float2 c = predb[p];
            float d = distf(c.x, c.y, gx, gy);
            if (d < bd || (d == bd && p < bi)) { bd = d; bi = p; }
        }
    } else {
        // bucket overflow (~impossible): exact coalesced re-filter
        for (int p = lane; p < PP; p += 64) {
            if ((int)labb[p] == g + 1) {
                float2 c = predb[p];
                float d = distf(c.x, c.y, gx, gy);
                if (d < bd || (d == bd && p < bi)) { bd = d; bi = p; }
            }
        }
    }

    // wave butterfly reduce: (min d, then min original index) — order-invariant
    for (int off = 32; off > 0; off >>= 1) {
        float od = __shfl_xor(bd, off, 64);
        int   oi = __shfl_xor(bi, off, 64);
        if (od < bd || (od == bd && oi < bi)) { bd = od; bi = oi; }
    }

    if (lane == 0) {
        int o = b * GG + g;
        out[o]               = (float)bi;   // src_idx
        out[BB * GG + o]     = (float)g;    // tgt_idx
        out[2 * BB * GG + o] = bd;          // costs
    }
}

extern "C" void kernel_launch(void* const* d_in, const int* in_sizes, int n_in,
                              void* d_out, int out_size, void* d_ws, size_t ws_size,
                              hipStream_t stream) {
    const float* pred = (const float*)d_in[0];
    const float* gt   = (const float*)d_in[1];
    const int*   lm   = (const int*)d_in[2];
    float* out = (float*)d_out;
    u16* labels = (u16*)d_ws;   // [B][P] u16, written before read, no init needed

    k_label<<<dim3(BB * PP / 256), dim3(256), 0, stream>>>(pred, lm, labels);
    k_match<<<dim3(BB * BPB), dim3(NTHR2), 0, stream>>>(pred, gt, labels, out);
}